// Round 1
// baseline (14667.662 us; speedup 1.0000x reference)
//
#include <hip/hip_runtime.h>
#include <hip/hip_bf16.h>
#include <hip/hip_fp16.h>

typedef unsigned short u16;
typedef unsigned int u32;
typedef __attribute__((ext_vector_type(4))) float f32x4;
typedef __attribute__((ext_vector_type(8))) _Float16 f16x8;

#define MFMAH(a, b, c) __builtin_amdgcn_mfma_f32_16x16x32_f16((a), (b), (c), 0, 0, 0)

__device__ __forceinline__ float bflo(u32 u) { return __uint_as_float(u << 16); }
__device__ __forceinline__ float bfhi(u32 u) { return __uint_as_float(u & 0xffff0000u); }
__device__ __forceinline__ float bf1(u16 u) { return __uint_as_float(((u32)u) << 16); }
__device__ __forceinline__ u16 f2bf(float f) {
    __hip_bfloat16 b = __float2bfloat16(f);
    return __builtin_bit_cast(u16, b);
}
__device__ __forceinline__ u16 f2h(float f) { return __builtin_bit_cast(u16, (_Float16)f); }
__device__ __forceinline__ u32 pk2h(float a, float b) {
    return (u32)f2h(a) | ((u32)f2h(b) << 16);
}

// ---------------------------------------------------------------------------
// Wave-uniform dtype sniff: 1 = fp32 inputs, 0 = bf16.
// ---------------------------------------------------------------------------
__device__ __forceinline__ int sniff_fp32(const void* Wr) {
    const uint4* p = (const uint4*)Wr;
    uint4 v = p[threadIdx.x & 15];
    u32 a[4] = {v.x, v.y, v.z, v.w};
    float m = 0.f;
#pragma unroll
    for (int i = 0; i < 4; ++i) {
        float lo = fabsf(bflo(a[i])), hi = fabsf(bfhi(a[i]));
        if (!(lo < 1e30f)) lo = 1e30f;
        if (!(hi < 1e30f)) hi = 1e30f;
        m = fmaxf(m, fmaxf(lo, hi));
    }
#pragma unroll
    for (int off = 32; off; off >>= 1) m = fmaxf(m, __shfl_xor(m, off, 64));
    return m > 100.f ? 1 : 0;
}

__device__ __forceinline__ float load1f(const void* base, size_t idx, int f32) {
    return f32 ? ((const float*)base)[idx] : bf1(((const u16*)base)[idx]);
}

// ---------------------------------------------------------------------------
// One-shot: convert W_r, W_z, W_h [256][512] and W_fc [256][256] to f16 in ws.
// Layout: wf16[g][n][512] for g=0..2, then wfc16[o][256] at half-offset 393216.
// ---------------------------------------------------------------------------
__global__ void wconv(const void* __restrict__ Wr, const void* __restrict__ Wz,
                      const void* __restrict__ Wh, const void* __restrict__ Wfc,
                      u16* __restrict__ wf16)
{
    const int f32 = sniff_fp32(Wr);
    const int gid = blockIdx.x * 256 + threadIdx.x;   // grid 448 -> 114688 threads
    const int e = gid * 4;                            // 458752 halfs total, exact
    const void* src;
    int off;
    if (e < 131072)      { src = Wr;  off = e; }
    else if (e < 262144) { src = Wz;  off = e - 131072; }
    else if (e < 393216) { src = Wh;  off = e - 262144; }
    else                 { src = Wfc; off = e - 393216; }
    uint2 o;
    if (f32) {
        float4 v = *(const float4*)((const float*)src + off);
        o.x = pk2h(v.x, v.y);
        o.y = pk2h(v.z, v.w);
    } else {
        uint2 v = *(const uint2*)((const u16*)src + off);
        o.x = pk2h(bflo(v.x), bfhi(v.x));
        o.y = pk2h(bflo(v.y), bfhi(v.y));
    }
    *(uint2*)(wf16 + e) = o;
}

// ---------------------------------------------------------------------------
// Precompute gates' x-part: gx[sl][b][g][n] = x_row . W_g[n][0:256] + b_g[n].
// Same proven tile structure as before, but: f16 A-staging, preconverted f16
// weights, f16 MFMA, and S-MAJOR output layout so the scan's per-step slice
// ([64 b][768]) is one contiguous 24 KB block.
// ---------------------------------------------------------------------------
__global__ __launch_bounds__(256, 2) void gru_pre(
    const void* __restrict__ x, const u16* __restrict__ wf16,
    const void* __restrict__ br, const void* __restrict__ bz, const void* __restrict__ bh,
    u16* __restrict__ gxc, int s0, int lgSc, const void* __restrict__ Wsniff)
{
    const int f32 = sniff_fp32(Wsniff);
    const int tid = threadIdx.x;
    const int R0 = blockIdx.x * 64;
    const int msk = (1 << lgSc) - 1;

    __shared__ __align__(16) _Float16 As[64][264];   // f16, +8 pad

    // ---- stage A: thread t -> row i = t>>2, k-quarter (t&3)*64, as f16 ----
    {
        const int i = tid >> 2;
        const int kq = (tid & 3) * 64;
        const int m = R0 + i;
        const int b = m >> lgSc;
        const int sl = m & msk;
        const size_t xbase = ((size_t)(b * 2048 + s0 + sl)) * 256 + kq;
        u16* dst = (u16*)&As[i][kq];
        if (f32) {
            const float4* p = (const float4*)((const float*)x + xbase);
#pragma unroll
            for (int j = 0; j < 8; ++j) {
                float4 v0 = p[2 * j], v1 = p[2 * j + 1];
                uint4 o;
                o.x = pk2h(v0.x, v0.y);
                o.y = pk2h(v0.z, v0.w);
                o.z = pk2h(v1.x, v1.y);
                o.w = pk2h(v1.z, v1.w);
                *(uint4*)(dst + j * 8) = o;
            }
        } else {
            const uint4* p = (const uint4*)((const u16*)x + xbase);
#pragma unroll
            for (int j = 0; j < 8; ++j) {
                uint4 v = p[j];
                uint4 o;
                o.x = pk2h(bflo(v.x), bfhi(v.x));
                o.y = pk2h(bflo(v.y), bfhi(v.y));
                o.z = pk2h(bflo(v.z), bfhi(v.z));
                o.w = pk2h(bflo(v.w), bfhi(v.w));
                *(uint4*)(dst + j * 8) = o;
            }
        }
    }
    __syncthreads();

    // ---- compute: wave wv handles groups gi = wv*3 + {0,1,2} ----
    const int wv = tid >> 6;
    const int lane = tid & 63;
    const int q = lane >> 4, l16 = lane & 15;

    for (int j = 0; j < 3; ++j) {
        const int gi = wv * 3 + j;            // 0..11
        const int g = gi >> 2;
        const int col0 = (gi & 3) * 64;
        const void* bias = (g == 0) ? br : ((g == 1) ? bz : bh);
        const size_t wbase = (size_t)(g * 256 + col0 + l16) * 512 + q * 8;

        f32x4 acc[4][4];
#pragma unroll
        for (int mt = 0; mt < 4; ++mt)
#pragma unroll
            for (int nt = 0; nt < 4; ++nt) acc[mt][nt] = (f32x4){0, 0, 0, 0};

#pragma unroll
        for (int k0 = 0; k0 < 256; k0 += 32) {
            f16x8 bfr[4];
#pragma unroll
            for (int nt = 0; nt < 4; ++nt)
                bfr[nt] = *(const f16x8*)(wf16 + wbase + (size_t)nt * 8192 + k0);
#pragma unroll
            for (int mt = 0; mt < 4; ++mt) {
                f16x8 af = *(const f16x8*)&As[mt * 16 + l16][k0 + q * 8];
#pragma unroll
                for (int nt = 0; nt < 4; ++nt)
                    acc[mt][nt] = MFMAH(af, bfr[nt], acc[mt][nt]);
            }
        }
        // D: col = l16, row = q*4 + r ; store s-major
#pragma unroll
        for (int nt = 0; nt < 4; ++nt) {
            const int col = col0 + nt * 16 + l16;
            const float bv = load1f(bias, col, f32);
#pragma unroll
            for (int mt = 0; mt < 4; ++mt)
#pragma unroll
                for (int r = 0; r < 4; ++r) {
                    const int m = R0 + mt * 16 + q * 4 + r;
                    const int b = m >> lgSc;
                    const int sl = m & msk;
                    gxc[((size_t)sl * 64 + b) * 768 + g * 256 + col] =
                        f2h(acc[mt][nt][r] + bv);
                }
        }
    }
}

// ---------------------------------------------------------------------------
// Sequential scan, MFMA edition. Grid 4 blocks x 768 threads; each block owns
// 16 batches. Waves 0-3 = r, 4-7 = z, 8-11 = h~; each wave owns 4 N-tiles
// (64 cols) and keeps W_g[cols][256:512] in 128 VGPRs as f16x8 fragments.
// Per step: ph1 = r,z MFMA (h from LDS) + sigmoid, r writes r*h; ph2 = h~
// MFMA (rh from LDS) + tanh + update. gx double-buffered in LDS, prefetched
// one step ahead via registers. Idle r/z waves stream h(s-1) to ws as f16
// for the projection kernel.
// ---------------------------------------------------------------------------
__global__ __launch_bounds__(768, 3) void gru_scan(
    const u16* __restrict__ gxc,   // [Sc][64][768] f16
    const u16* __restrict__ wf16,  // [3][256][512] f16
    float* __restrict__ h_state,
    u16* __restrict__ hs,          // [64][Sc][256] f16
    void* __restrict__ outbase,    // h_last at element 33554432
    const void* __restrict__ Wsniff,
    int Sc, int first, int last)
{
    const int f32o = sniff_fp32(Wsniff);
    const int tid = threadIdx.x;
    const int wv = tid >> 6, lane = tid & 63;
    const int q = lane >> 4, l16 = lane & 15;
    const int gate = wv >> 2;          // 0=r 1=z 2=h~
    const int wsub = wv & 3;
    const int b0 = blockIdx.x * 16;
    const int colb = wsub * 64 + l16;

    __shared__ __align__(16) _Float16 h_h[16][264];
    __shared__ __align__(16) _Float16 rh_h[16][264];
    __shared__ __align__(16) float    z_s[16][260];
    __shared__ __align__(16) float    h_f[16][260];
    __shared__ __align__(16) _Float16 gxl[2][16][776];

    // persistent weight fragments: W_gate[col][256 + k]
    f16x8 w[4][8];
#pragma unroll
    for (int nt = 0; nt < 4; ++nt) {
        const size_t rowb = (size_t)(gate * 256 + colb + nt * 16) * 512 + 256 + q * 8;
#pragma unroll
        for (int kk = 0; kk < 8; ++kk)
            w[nt][kk] = *(const f16x8*)(wf16 + rowb + kk * 32);
    }

    // init h (h~ waves cover all 16x256)
    if (gate == 2) {
#pragma unroll
        for (int nt = 0; nt < 4; ++nt) {
            const int col = colb + nt * 16;
#pragma unroll
            for (int r = 0; r < 4; ++r) {
                const int b = q * 4 + r;
                float h0 = first ? 0.f : h_state[(size_t)(b0 + b) * 256 + col];
                h_f[b][col] = h0;
                h_h[b][col] = (_Float16)h0;
            }
        }
    }
    // stage gx(s=0): all 768 threads, 16 halfs each (12288 = 16*768 exact)
    const int tb = tid / 48, tc = (tid % 48) * 16;
    {
        const u16* gs = gxc + (size_t)(b0 + tb) * 768 + tc;
        uint4 a0 = *(const uint4*)gs, a1 = *(const uint4*)(gs + 8);
        u16* d = (u16*)&gxl[0][tb][tc];
        *(uint4*)d = a0;
        *(uint4*)(d + 8) = a1;
    }
    __syncthreads();

    const size_t gstep = 49152;   // 64*768 halfs per step
    uint4 pf0 = {0, 0, 0, 0}, pf1 = {0, 0, 0, 0};

    for (int s = 0; s < Sc; ++s) {
        const int pc = s & 1;
        // prefetch next step's gx into regs (consumed at end of ph2)
        if (s + 1 < Sc) {
            const u16* gs = gxc + (size_t)(s + 1) * gstep + (size_t)(b0 + tb) * 768 + tc;
            pf0 = *(const uint4*)gs;
            pf1 = *(const uint4*)(gs + 8);
        }
        if (gate < 2) {
            // stream h(s-1) to hs (f16) -- 512 threads x 8 halfs = 16x256
            if (s > 0) {
                const int cb = tid >> 5, cc = (tid & 31) * 8;
                uint4 hv = *(const uint4*)&h_h[cb][cc];
                *(uint4*)(hs + ((size_t)(b0 + cb) * Sc + (s - 1)) * 256 + cc) = hv;
            }
            f32x4 acc[4];
#pragma unroll
            for (int nt = 0; nt < 4; ++nt) acc[nt] = (f32x4){0.f, 0.f, 0.f, 0.f};
#pragma unroll
            for (int kk = 0; kk < 8; ++kk) {
                f16x8 a = *(const f16x8*)&h_h[l16][kk * 32 + q * 8];
#pragma unroll
                for (int nt = 0; nt < 4; ++nt)
                    acc[nt] = MFMAH(a, w[nt][kk], acc[nt]);
            }
#pragma unroll
            for (int nt = 0; nt < 4; ++nt) {
                const int col = colb + nt * 16;
#pragma unroll
                for (int r = 0; r < 4; ++r) {
                    const int b = q * 4 + r;
                    float p = acc[nt][r] + (float)gxl[pc][b][gate * 256 + col];
                    float sg = __fdividef(1.f, 1.f + __expf(-p));
                    if (gate == 0) rh_h[b][col] = (_Float16)(sg * h_f[b][col]);
                    else           z_s[b][col] = sg;
                }
            }
        }
        __syncthreads();
        if (gate == 2) {
            f32x4 acc[4];
#pragma unroll
            for (int nt = 0; nt < 4; ++nt) acc[nt] = (f32x4){0.f, 0.f, 0.f, 0.f};
#pragma unroll
            for (int kk = 0; kk < 8; ++kk) {
                f16x8 a = *(const f16x8*)&rh_h[l16][kk * 32 + q * 8];
#pragma unroll
                for (int nt = 0; nt < 4; ++nt)
                    acc[nt] = MFMAH(a, w[nt][kk], acc[nt]);
            }
#pragma unroll
            for (int nt = 0; nt < 4; ++nt) {
                const int col = colb + nt * 16;
#pragma unroll
                for (int r = 0; r < 4; ++r) {
                    const int b = q * 4 + r;
                    float p = acc[nt][r] + (float)gxl[pc][b][512 + col];
                    p = fminf(fmaxf(p, -15.f), 15.f);
                    float e = __expf(2.f * p);
                    float ht = 1.f - __fdividef(2.f, e + 1.f);
                    float hold = h_f[b][col];
                    float hn = fmaf(z_s[b][col], ht - hold, hold);
                    h_f[b][col] = hn;
                    h_h[b][col] = (_Float16)hn;
                    if (s == Sc - 1) {
                        h_state[(size_t)(b0 + b) * 256 + col] = hn;
                        if (last) {
                            const size_t li = (size_t)33554432 + (size_t)(b0 + b) * 256 + col;
                            if (f32o) ((float*)outbase)[li] = hn;
                            else      ((u16*)outbase)[li] = f2bf(hn);
                        }
                    }
                }
            }
            if (s + 1 < Sc) {
                u16* d = (u16*)&gxl[pc ^ 1][tb][tc];
                *(uint4*)d = pf0;
                *(uint4*)(d + 8) = pf1;
            }
        } else {
            if (s + 1 < Sc) {
                u16* d = (u16*)&gxl[pc ^ 1][tb][tc];
                *(uint4*)d = pf0;
                *(uint4*)(d + 8) = pf1;
            }
        }
        __syncthreads();
    }
    // final hs row (h(Sc-1))
    if (tid < 512) {
        const int cb = tid >> 5, cc = (tid & 31) * 8;
        uint4 hv = *(const uint4*)&h_h[cb][cc];
        *(uint4*)(hs + ((size_t)(b0 + cb) * Sc + (Sc - 1)) * 256 + cc) = hv;
    }
}

// ---------------------------------------------------------------------------
// Output projection: reads hs (f16, ws) and wfc16 (f16, ws), writes d_out.
// 64 rows per block, 4 waves x 16 rows, 16 N-tiles each.
// ---------------------------------------------------------------------------
__global__ __launch_bounds__(256) void gru_proj(
    const u16* __restrict__ wfc16, const void* __restrict__ bfc,
    const void* __restrict__ Wsniff, const u16* __restrict__ hs,
    void* __restrict__ outb, int s0, int lgSc)
{
    const int f32 = sniff_fp32(Wsniff);
    const int lane = threadIdx.x & 63;
    const int wave = threadIdx.x >> 6;
    const int q = lane >> 4, l16 = lane & 15;
    const int msk = (1 << lgSc) - 1;
    const int m0 = blockIdx.x * 64 + wave * 16;
    const size_t aidx = (size_t)(m0 + l16) * 256 + q * 8;
    const size_t widx = (size_t)l16 * 256 + q * 8;
    f32x4 acc[16];
#pragma unroll
    for (int t = 0; t < 16; ++t) acc[t] = (f32x4){0, 0, 0, 0};
#pragma unroll 2
    for (int k0 = 0; k0 < 256; k0 += 32) {
        f16x8 af = *(const f16x8*)(hs + aidx + k0);
#pragma unroll
        for (int t = 0; t < 16; ++t) {
            f16x8 bfg = *(const f16x8*)(wfc16 + widx + (size_t)t * 4096 + k0);
            acc[t] = MFMAH(af, bfg, acc[t]);
        }
    }
#pragma unroll
    for (int t = 0; t < 16; ++t) {
        const int col = t * 16 + l16;
        const float bv = load1f(bfc, col, f32);
#pragma unroll
        for (int r = 0; r < 4; ++r) {
            const int m = m0 + q * 4 + r;
            const int b = m >> lgSc;
            const int sl = m & msk;
            const size_t oidx = ((size_t)b * 2048 + s0 + sl) * 256 + col;
            float v = acc[t][r] + bv;
            if (f32) ((float*)outb)[oidx] = v;
            else     ((u16*)outb)[oidx] = f2bf(v);
        }
    }
}

// ---------------------------------------------------------------------------
// ws layout: [0,64K) h_state f32 | [64K, 64K+917504) wf16 | [1M, 1M+Sc*96K)
// gxc f16 (s-major) | then Sc*32K hs f16.  Per-chunk: pre -> scan -> proj.
// ---------------------------------------------------------------------------
extern "C" void kernel_launch(void* const* d_in, const int* in_sizes, int n_in,
                              void* d_out, int out_size, void* d_ws, size_t ws_size,
                              hipStream_t stream) {
    (void)in_sizes; (void)n_in; (void)out_size;
    const void* x   = d_in[0];
    const void* Wr  = d_in[1];
    const void* br  = d_in[2];
    const void* Wz  = d_in[3];
    const void* bz  = d_in[4];
    const void* Wh  = d_in[5];
    const void* bh  = d_in[6];
    const void* Wfc = d_in[7];
    const void* bfc = d_in[8];

    float* h_state = (float*)d_ws;                        // 64*256 fp32 = 64KB
    u16*   wf16    = (u16*)((char*)d_ws + 65536);         // 458752 halfs

    int lgSc = 11;
    while (lgSc > 0 &&
           (size_t)1048576 + ((size_t)131072 << lgSc) > ws_size) --lgSc;
    const int Sc = 1 << lgSc;
    u16* gxc = (u16*)((char*)d_ws + 1048576);
    u16* hs  = (u16*)((char*)d_ws + 1048576 + (size_t)Sc * 98304);

    wconv<<<448, 256, 0, stream>>>(Wr, Wz, Wh, Wfc, wf16);

    for (int s0 = 0; s0 < 2048; s0 += Sc) {
        gru_pre<<<Sc, 256, 0, stream>>>(x, wf16, br, bz, bh, gxc, s0, lgSc, Wr);
        gru_scan<<<4, 768, 0, stream>>>(gxc, wf16, h_state, hs, d_out, Wr,
                                        Sc, (s0 == 0) ? 1 : 0,
                                        (s0 + Sc == 2048) ? 1 : 0);
        gru_proj<<<Sc, 256, 0, stream>>>(wf16 + 393216, bfc, Wr, hs, d_out,
                                         s0, lgSc);
    }
}

// Round 2
// 5669.735 us; speedup vs baseline: 2.5870x; 2.5870x over previous
//
#include <hip/hip_runtime.h>
#include <hip/hip_bf16.h>
#include <hip/hip_fp16.h>

typedef unsigned short u16;
typedef unsigned int u32;
typedef __attribute__((ext_vector_type(4))) float f32x4;
typedef __attribute__((ext_vector_type(8))) _Float16 f16x8;

#define MFMAH(a, b, c) __builtin_amdgcn_mfma_f32_16x16x32_f16((a), (b), (c), 0, 0, 0)

__device__ __forceinline__ float bflo(u32 u) { return __uint_as_float(u << 16); }
__device__ __forceinline__ float bfhi(u32 u) { return __uint_as_float(u & 0xffff0000u); }
__device__ __forceinline__ float bf1(u16 u) { return __uint_as_float(((u32)u) << 16); }
__device__ __forceinline__ u16 f2bf(float f) {
    __hip_bfloat16 b = __float2bfloat16(f);
    return __builtin_bit_cast(u16, b);
}
__device__ __forceinline__ u16 f2h(float f) { return __builtin_bit_cast(u16, (_Float16)f); }
__device__ __forceinline__ u32 pk2h(float a, float b) {
    return (u32)f2h(a) | ((u32)f2h(b) << 16);
}
__device__ __forceinline__ float fexp2(float x) { return __builtin_amdgcn_exp2f(x); }
__device__ __forceinline__ float frcp(float x) { return __builtin_amdgcn_rcpf(x); }

// ---------------------------------------------------------------------------
// Wave-uniform dtype sniff: 1 = fp32 inputs, 0 = bf16.
// ---------------------------------------------------------------------------
__device__ __forceinline__ int sniff_fp32(const void* Wr) {
    const uint4* p = (const uint4*)Wr;
    uint4 v = p[threadIdx.x & 15];
    u32 a[4] = {v.x, v.y, v.z, v.w};
    float m = 0.f;
#pragma unroll
    for (int i = 0; i < 4; ++i) {
        float lo = fabsf(bflo(a[i])), hi = fabsf(bfhi(a[i]));
        if (!(lo < 1e30f)) lo = 1e30f;
        if (!(hi < 1e30f)) hi = 1e30f;
        m = fmaxf(m, fmaxf(lo, hi));
    }
#pragma unroll
    for (int off = 32; off; off >>= 1) m = fmaxf(m, __shfl_xor(m, off, 64));
    return m > 100.f ? 1 : 0;
}

__device__ __forceinline__ float load1f(const void* base, size_t idx, int f32) {
    return f32 ? ((const float*)base)[idx] : bf1(((const u16*)base)[idx]);
}

// ---------------------------------------------------------------------------
// One-shot: convert W_r, W_z, W_h [256][512] and W_fc [256][256] to f16 in ws.
// Layout: wf16[g][n][512] for g=0..2, then wfc16[o][256] at half-offset 393216.
// ---------------------------------------------------------------------------
__global__ void wconv(const void* __restrict__ Wr, const void* __restrict__ Wz,
                      const void* __restrict__ Wh, const void* __restrict__ Wfc,
                      u16* __restrict__ wf16)
{
    const int f32 = sniff_fp32(Wr);
    const int gid = blockIdx.x * 256 + threadIdx.x;   // grid 448 -> 114688 threads
    const int e = gid * 4;                            // 458752 halfs total, exact
    const void* src;
    int off;
    if (e < 131072)      { src = Wr;  off = e; }
    else if (e < 262144) { src = Wz;  off = e - 131072; }
    else if (e < 393216) { src = Wh;  off = e - 262144; }
    else                 { src = Wfc; off = e - 393216; }
    uint2 o;
    if (f32) {
        float4 v = *(const float4*)((const float*)src + off);
        o.x = pk2h(v.x, v.y);
        o.y = pk2h(v.z, v.w);
    } else {
        uint2 v = *(const uint2*)((const u16*)src + off);
        o.x = pk2h(bflo(v.x), bfhi(v.x));
        o.y = pk2h(bflo(v.y), bfhi(v.y));
    }
    *(uint2*)(wf16 + e) = o;
}

// ---------------------------------------------------------------------------
// Precompute gates' x-part: gx[sl][b][g][n] = x_row . W_g[n][0:256] + b_g[n].
// f16 A-staging, preconverted f16 weights, f16 MFMA, s-major output layout
// ([sl][64][768]) so the scan's per-step slice is one contiguous 24 KB block.
// ---------------------------------------------------------------------------
__global__ __launch_bounds__(256, 2) void gru_pre(
    const void* __restrict__ x, const u16* __restrict__ wf16,
    const void* __restrict__ br, const void* __restrict__ bz, const void* __restrict__ bh,
    u16* __restrict__ gxc, int s0, int lgSc, const void* __restrict__ Wsniff)
{
    const int f32 = sniff_fp32(Wsniff);
    const int tid = threadIdx.x;
    const int R0 = blockIdx.x * 64;
    const int msk = (1 << lgSc) - 1;

    __shared__ __align__(16) _Float16 As[64][264];   // f16, +8 pad

    // ---- stage A: thread t -> row i = t>>2, k-quarter (t&3)*64, as f16 ----
    {
        const int i = tid >> 2;
        const int kq = (tid & 3) * 64;
        const int m = R0 + i;
        const int b = m >> lgSc;
        const int sl = m & msk;
        const size_t xbase = ((size_t)(b * 2048 + s0 + sl)) * 256 + kq;
        u16* dst = (u16*)&As[i][kq];
        if (f32) {
            const float4* p = (const float4*)((const float*)x + xbase);
#pragma unroll
            for (int j = 0; j < 8; ++j) {
                float4 v0 = p[2 * j], v1 = p[2 * j + 1];
                uint4 o;
                o.x = pk2h(v0.x, v0.y);
                o.y = pk2h(v0.z, v0.w);
                o.z = pk2h(v1.x, v1.y);
                o.w = pk2h(v1.z, v1.w);
                *(uint4*)(dst + j * 8) = o;
            }
        } else {
            const uint4* p = (const uint4*)((const u16*)x + xbase);
#pragma unroll
            for (int j = 0; j < 8; ++j) {
                uint4 v = p[j];
                uint4 o;
                o.x = pk2h(bflo(v.x), bfhi(v.x));
                o.y = pk2h(bflo(v.y), bfhi(v.y));
                o.z = pk2h(bflo(v.z), bfhi(v.z));
                o.w = pk2h(bflo(v.w), bfhi(v.w));
                *(uint4*)(dst + j * 8) = o;
            }
        }
    }
    __syncthreads();

    // ---- compute: wave wv handles groups gi = wv*3 + {0,1,2} ----
    const int wv = tid >> 6;
    const int lane = tid & 63;
    const int q = lane >> 4, l16 = lane & 15;

    for (int j = 0; j < 3; ++j) {
        const int gi = wv * 3 + j;            // 0..11
        const int g = gi >> 2;
        const int col0 = (gi & 3) * 64;
        const void* bias = (g == 0) ? br : ((g == 1) ? bz : bh);
        const size_t wbase = (size_t)(g * 256 + col0 + l16) * 512 + q * 8;

        f32x4 acc[4][4];
#pragma unroll
        for (int mt = 0; mt < 4; ++mt)
#pragma unroll
            for (int nt = 0; nt < 4; ++nt) acc[mt][nt] = (f32x4){0, 0, 0, 0};

#pragma unroll
        for (int k0 = 0; k0 < 256; k0 += 32) {
            f16x8 bfr[4];
#pragma unroll
            for (int nt = 0; nt < 4; ++nt)
                bfr[nt] = *(const f16x8*)(wf16 + wbase + (size_t)nt * 8192 + k0);
#pragma unroll
            for (int mt = 0; mt < 4; ++mt) {
                f16x8 af = *(const f16x8*)&As[mt * 16 + l16][k0 + q * 8];
#pragma unroll
                for (int nt = 0; nt < 4; ++nt)
                    acc[mt][nt] = MFMAH(af, bfr[nt], acc[mt][nt]);
            }
        }
        // D: col = l16, row = q*4 + r ; store s-major
#pragma unroll
        for (int nt = 0; nt < 4; ++nt) {
            const int col = col0 + nt * 16 + l16;
            const float bv = load1f(bias, col, f32);
#pragma unroll
            for (int mt = 0; mt < 4; ++mt)
#pragma unroll
                for (int r = 0; r < 4; ++r) {
                    const int m = R0 + mt * 16 + q * 4 + r;
                    const int b = m >> lgSc;
                    const int sl = m & msk;
                    gxc[((size_t)sl * 64 + b) * 768 + g * 256 + col] =
                        f2h(acc[mt][nt][r] + bv);
                }
        }
    }
}

// ---------------------------------------------------------------------------
// Async global->LDS staging of one step's gx slice (24576 B, linear copy).
// Per wave: 3 issues of 1024 B (uniform LDS base + lane*16).
// ---------------------------------------------------------------------------
__device__ __forceinline__ void stage_gx(const u16* gsrc, _Float16* lbuf,
                                         int wv, int lane) {
#if __has_builtin(__builtin_amdgcn_global_load_lds)
#pragma unroll
    for (int i = 0; i < 3; ++i) {
        const void* g = (const void*)((const char*)gsrc + wv * 3072 + i * 1024 + lane * 16);
        void* l = (void*)((char*)lbuf + wv * 3072 + i * 1024);
        __builtin_amdgcn_global_load_lds(
            (const __attribute__((address_space(1))) void*)g,
            (__attribute__((address_space(3))) void*)l, 16, 0, 0);
    }
#else
#pragma unroll
    for (int i = 0; i < 3; ++i) {
        uint4 v = *(const uint4*)((const char*)gsrc + wv * 3072 + i * 1024 + lane * 16);
        *(uint4*)((char*)lbuf + wv * 3072 + i * 1024 + lane * 16) = v;
    }
#endif
}

// ---------------------------------------------------------------------------
// Sequential scan, MFMA edition v2 (register-budget-correct).
// Grid 4 x 512 threads (8 waves, __launch_bounds__(512,2) -> 256 VGPR cap).
// Each wave owns 32 cols; holds W_r,W_z (128 VGPR) for ph1 and W_h (64 VGPR)
// for ph2 -> 192 persistent regs, fits. z and h_old live in REGISTERS
// (same wave computes z, h~ and the update for its cols). gx triple-buffered
// in LDS via global_load_lds (prefetch 2 steps ahead -> HBM latency hidden).
// ---------------------------------------------------------------------------
__global__ __launch_bounds__(512, 2) void gru_scan(
    const u16* __restrict__ gxc,   // [Sc][64][768] f16
    const u16* __restrict__ wf16,  // [3][256][512] f16
    float* __restrict__ h_state,
    u16* __restrict__ hs,          // [64][Sc][256] f16
    void* __restrict__ outbase,    // h_last at element 33554432
    const void* __restrict__ Wsniff,
    int Sc, int first, int last)
{
    const int f32o = sniff_fp32(Wsniff);
    const int tid = threadIdx.x;
    const int wv = tid >> 6, lane = tid & 63;
    const int q = lane >> 4, l16 = lane & 15;
    const int b0 = blockIdx.x * 16;

    __shared__ __align__(16) _Float16 h_h[16][776];    // +8 pad: stride 1552 B
    __shared__ __align__(16) _Float16 rh_h[16][776];
    __shared__ __align__(16) _Float16 gxl[3][16][768]; // UNPADDED (linear copy)

    // ---- persistent weights: ph1 tiles {r0,r1,z0,z1}, ph2 tiles {h0,h1} ----
    f16x8 w1[4][8];
#pragma unroll
    for (int t = 0; t < 4; ++t) {
        const int g = t >> 1;
        const size_t rowb =
            (size_t)(g * 256 + wv * 32 + (t & 1) * 16 + l16) * 512 + 256 + q * 8;
#pragma unroll
        for (int kk = 0; kk < 8; ++kk)
            w1[t][kk] = *(const f16x8*)(wf16 + rowb + kk * 32);
    }
    f16x8 w2[2][8];
#pragma unroll
    for (int t = 0; t < 2; ++t) {
        const size_t rowb = (size_t)(512 + wv * 32 + t * 16 + l16) * 512 + 256 + q * 8;
#pragma unroll
        for (int kk = 0; kk < 8; ++kk)
            w2[t][kk] = *(const f16x8*)(wf16 + rowb + kk * 32);
    }

    // ---- init h (registers + LDS f16) ----
    float h_old[2][4];
#pragma unroll
    for (int t = 0; t < 2; ++t) {
        const int col = wv * 32 + t * 16 + l16;
#pragma unroll
        for (int r = 0; r < 4; ++r) {
            const int b = q * 4 + r;
            float h0 = first ? 0.f : h_state[(size_t)(b0 + b) * 256 + col];
            h_old[t][r] = h0;
            h_h[b][col] = (_Float16)h0;
        }
    }

    const u16* gbase = gxc + (size_t)b0 * 768;
    _Float16* g_cur = &gxl[0][0][0];
    _Float16* g_nx1 = &gxl[1][0][0];
    _Float16* g_nx2 = &gxl[2][0][0];

    // prologue: stage s=0, s=1
    stage_gx(gbase, g_cur, wv, lane);
    if (Sc > 1) stage_gx(gbase + 49152, g_nx1, wv, lane);
    __syncthreads();

    for (int s = 0; s < Sc; ++s) {
        // stream h(s-1) to hs (coalesced; reads h_h which ph1 never writes)
        if (s > 0) {
            const int cb = tid >> 5, cc = (tid & 31) * 8;
            uint4 hv = *(const uint4*)&h_h[cb][cc];
            *(uint4*)(hs + ((size_t)(b0 + cb) * Sc + (s - 1)) * 256 + cc) = hv;
        }
        // prefetch gx(s+2) into the buffer freed at the end of step s-1
        if (s + 2 < Sc) stage_gx(gbase + (size_t)(s + 2) * 49152, g_nx2, wv, lane);

        // ---- phase 1: r and z (A = h_h, B = w1 regs) ----
        f32x4 acc[4];
#pragma unroll
        for (int t = 0; t < 4; ++t) acc[t] = (f32x4){0.f, 0.f, 0.f, 0.f};
#pragma unroll
        for (int kk = 0; kk < 8; ++kk) {
            f16x8 a = *(const f16x8*)&h_h[l16][kk * 32 + q * 8];
#pragma unroll
            for (int t = 0; t < 4; ++t) acc[t] = MFMAH(a, w1[t][kk], acc[t]);
        }
        float z_reg[2][4];
#pragma unroll
        for (int t = 0; t < 4; ++t) {
            const int g = t >> 1;
            const int tt = t & 1;
            const int col = wv * 32 + tt * 16 + l16;
#pragma unroll
            for (int r = 0; r < 4; ++r) {
                const int b = q * 4 + r;
                float gx = (float)g_cur[b * 768 + g * 256 + col];
                float p = acc[t][r] + gx;
                float sg = frcp(1.f + fexp2(-1.44269504f * p));
                if (g == 0) rh_h[b][col] = (_Float16)(sg * h_old[tt][r]);
                else        z_reg[tt][r] = sg;
            }
        }
        __syncthreads();

        // ---- phase 2: h~ (A = rh_h, B = w2 regs) + update ----
        f32x4 acch[2];
#pragma unroll
        for (int t = 0; t < 2; ++t) acch[t] = (f32x4){0.f, 0.f, 0.f, 0.f};
#pragma unroll
        for (int kk = 0; kk < 8; ++kk) {
            f16x8 a = *(const f16x8*)&rh_h[l16][kk * 32 + q * 8];
#pragma unroll
            for (int t = 0; t < 2; ++t) acch[t] = MFMAH(a, w2[t][kk], acch[t]);
        }
#pragma unroll
        for (int t = 0; t < 2; ++t) {
            const int col = wv * 32 + t * 16 + l16;
#pragma unroll
            for (int r = 0; r < 4; ++r) {
                const int b = q * 4 + r;
                float gx = (float)g_cur[b * 768 + 512 + col];
                float p = acch[t][r] + gx;
                // tanh(p) = 1 - 2/(exp2(2*log2e*p)+1); IEEE limits give +-1.
                float e = fexp2(2.88539008f * p);
                float ht = 1.f - 2.f * frcp(e + 1.f);
                float hold = h_old[t][r];
                float hn = fmaf(z_reg[t][r], ht - hold, hold);
                h_old[t][r] = hn;
                h_h[b][col] = (_Float16)hn;
                if (s == Sc - 1) {
                    h_state[(size_t)(b0 + b) * 256 + col] = hn;
                    if (last) {
                        const size_t li = (size_t)33554432 + (size_t)(b0 + b) * 256 + col;
                        if (f32o) ((float*)outbase)[li] = hn;
                        else      ((u16*)outbase)[li] = f2bf(hn);
                    }
                }
            }
        }
        // rotate gx triple-buffer
        _Float16* tmp = g_cur; g_cur = g_nx1; g_nx1 = g_nx2; g_nx2 = tmp;
        __syncthreads();
    }
    // final hs row: h(Sc-1)
    {
        const int cb = tid >> 5, cc = (tid & 31) * 8;
        uint4 hv = *(const uint4*)&h_h[cb][cc];
        *(uint4*)(hs + ((size_t)(b0 + cb) * Sc + (Sc - 1)) * 256 + cc) = hv;
    }
}

// ---------------------------------------------------------------------------
// Output projection: reads hs (f16, ws) and wfc16 (f16, ws), writes d_out.
// 64 rows per block, 4 waves x 16 rows, 16 N-tiles each.
// ---------------------------------------------------------------------------
__global__ __launch_bounds__(256) void gru_proj(
    const u16* __restrict__ wfc16, const void* __restrict__ bfc,
    const void* __restrict__ Wsniff, const u16* __restrict__ hs,
    void* __restrict__ outb, int s0, int lgSc)
{
    const int f32 = sniff_fp32(Wsniff);
    const int lane = threadIdx.x & 63;
    const int wave = threadIdx.x >> 6;
    const int q = lane >> 4, l16 = lane & 15;
    const int msk = (1 << lgSc) - 1;
    const int m0 = blockIdx.x * 64 + wave * 16;
    const size_t aidx = (size_t)(m0 + l16) * 256 + q * 8;
    const size_t widx = (size_t)l16 * 256 + q * 8;
    f32x4 acc[16];
#pragma unroll
    for (int t = 0; t < 16; ++t) acc[t] = (f32x4){0, 0, 0, 0};
#pragma unroll 2
    for (int k0 = 0; k0 < 256; k0 += 32) {
        f16x8 af = *(const f16x8*)(hs + aidx + k0);
#pragma unroll
        for (int t = 0; t < 16; ++t) {
            f16x8 bfg = *(const f16x8*)(wfc16 + widx + (size_t)t * 4096 + k0);
            acc[t] = MFMAH(af, bfg, acc[t]);
        }
    }
#pragma unroll
    for (int t = 0; t < 16; ++t) {
        const int col = t * 16 + l16;
        const float bv = load1f(bfc, col, f32);
#pragma unroll
        for (int r = 0; r < 4; ++r) {
            const int m = m0 + q * 4 + r;
            const int b = m >> lgSc;
            const int sl = m & msk;
            const size_t oidx = ((size_t)b * 2048 + s0 + sl) * 256 + col;
            float v = acc[t][r] + bv;
            if (f32) ((float*)outb)[oidx] = v;
            else     ((u16*)outb)[oidx] = f2bf(v);
        }
    }
}

// ---------------------------------------------------------------------------
// ws layout: [0,64K) h_state f32 | [64K,64K+917504) wf16 | [1M, 1M+Sc*96K)
// gxc f16 (s-major) | then Sc*32K hs f16.  Per-chunk: pre -> scan -> proj.
// ---------------------------------------------------------------------------
extern "C" void kernel_launch(void* const* d_in, const int* in_sizes, int n_in,
                              void* d_out, int out_size, void* d_ws, size_t ws_size,
                              hipStream_t stream) {
    (void)in_sizes; (void)n_in; (void)out_size;
    const void* x   = d_in[0];
    const void* Wr  = d_in[1];
    const void* br  = d_in[2];
    const void* Wz  = d_in[3];
    const void* bz  = d_in[4];
    const void* Wh  = d_in[5];
    const void* bh  = d_in[6];
    const void* Wfc = d_in[7];
    const void* bfc = d_in[8];

    float* h_state = (float*)d_ws;                        // 64*256 fp32 = 64KB
    u16*   wf16    = (u16*)((char*)d_ws + 65536);         // 458752 halfs

    int lgSc = 11;
    while (lgSc > 0 &&
           (size_t)1048576 + ((size_t)131072 << lgSc) > ws_size) --lgSc;
    const int Sc = 1 << lgSc;
    u16* gxc = (u16*)((char*)d_ws + 1048576);
    u16* hs  = (u16*)((char*)d_ws + 1048576 + (size_t)Sc * 98304);

    wconv<<<448, 256, 0, stream>>>(Wr, Wz, Wh, Wfc, wf16);

    for (int s0 = 0; s0 < 2048; s0 += Sc) {
        gru_pre<<<Sc, 256, 0, stream>>>(x, wf16, br, bz, bh, gxc, s0, lgSc, Wr);
        gru_scan<<<4, 512, 0, stream>>>(gxc, wf16, h_state, hs, d_out, Wr,
                                        Sc, (s0 == 0) ? 1 : 0,
                                        (s0 + Sc == 2048) ? 1 : 0);
        gru_proj<<<Sc, 256, 0, stream>>>(wf16 + 393216, bfc, Wr, hs, d_out,
                                         s0, lgSc);
    }
}

// Round 3
// 5511.620 us; speedup vs baseline: 2.6612x; 1.0287x over previous
//
#include <hip/hip_runtime.h>
#include <hip/hip_bf16.h>
#include <hip/hip_fp16.h>

typedef unsigned short u16;
typedef unsigned int u32;
typedef __attribute__((ext_vector_type(4))) float f32x4;
typedef __attribute__((ext_vector_type(8))) _Float16 f16x8;

#define MFMAH(a, b, c) __builtin_amdgcn_mfma_f32_16x16x32_f16((a), (b), (c), 0, 0, 0)

// Raw barrier: LDS-drain only -- does NOT drain vmcnt (keeps global_load_lds
// prefetch in flight across barriers; the m97 vmcnt(0)-drain is the stall
// we're removing vs round 2's __syncthreads()).
#define BAR() asm volatile("s_waitcnt lgkmcnt(0)\ns_barrier" ::: "memory")
// Counted vmem wait before consuming staged LDS data (T4). sched_barrier
// stops the scheduler hoisting the dependent ds_reads above it (rule #18).
#define WAITV7()                                          \
    do {                                                  \
        asm volatile("s_waitcnt vmcnt(7)" ::: "memory");  \
        __builtin_amdgcn_sched_barrier(0);                \
    } while (0)

__device__ __forceinline__ float bflo(u32 u) { return __uint_as_float(u << 16); }
__device__ __forceinline__ float bfhi(u32 u) { return __uint_as_float(u & 0xffff0000u); }
__device__ __forceinline__ float bf1(u16 u) { return __uint_as_float(((u32)u) << 16); }
__device__ __forceinline__ u16 f2bf(float f) {
    __hip_bfloat16 b = __float2bfloat16(f);
    return __builtin_bit_cast(u16, b);
}
__device__ __forceinline__ u16 f2h(float f) { return __builtin_bit_cast(u16, (_Float16)f); }
__device__ __forceinline__ u32 pk2h(float a, float b) {
    return (u32)f2h(a) | ((u32)f2h(b) << 16);
}
__device__ __forceinline__ float fexp2(float x) { return __builtin_amdgcn_exp2f(x); }
__device__ __forceinline__ float frcp(float x) { return __builtin_amdgcn_rcpf(x); }

// ---------------------------------------------------------------------------
// Wave-uniform dtype sniff: 1 = fp32 inputs, 0 = bf16.
// ---------------------------------------------------------------------------
__device__ __forceinline__ int sniff_fp32(const void* Wr) {
    const uint4* p = (const uint4*)Wr;
    uint4 v = p[threadIdx.x & 15];
    u32 a[4] = {v.x, v.y, v.z, v.w};
    float m = 0.f;
#pragma unroll
    for (int i = 0; i < 4; ++i) {
        float lo = fabsf(bflo(a[i])), hi = fabsf(bfhi(a[i]));
        if (!(lo < 1e30f)) lo = 1e30f;
        if (!(hi < 1e30f)) hi = 1e30f;
        m = fmaxf(m, fmaxf(lo, hi));
    }
#pragma unroll
    for (int off = 32; off; off >>= 1) m = fmaxf(m, __shfl_xor(m, off, 64));
    return m > 100.f ? 1 : 0;
}

__device__ __forceinline__ float load1f(const void* base, size_t idx, int f32) {
    return f32 ? ((const float*)base)[idx] : bf1(((const u16*)base)[idx]);
}

// ---------------------------------------------------------------------------
// One-shot: convert W_r, W_z, W_h [256][512] and W_fc [256][256] to f16 in ws.
// ---------------------------------------------------------------------------
__global__ void wconv(const void* __restrict__ Wr, const void* __restrict__ Wz,
                      const void* __restrict__ Wh, const void* __restrict__ Wfc,
                      u16* __restrict__ wf16)
{
    const int f32 = sniff_fp32(Wr);
    const int gid = blockIdx.x * 256 + threadIdx.x;
    const int e = gid * 4;
    const void* src;
    int off;
    if (e < 131072)      { src = Wr;  off = e; }
    else if (e < 262144) { src = Wz;  off = e - 131072; }
    else if (e < 393216) { src = Wh;  off = e - 262144; }
    else                 { src = Wfc; off = e - 393216; }
    uint2 o;
    if (f32) {
        float4 v = *(const float4*)((const float*)src + off);
        o.x = pk2h(v.x, v.y);
        o.y = pk2h(v.z, v.w);
    } else {
        uint2 v = *(const uint2*)((const u16*)src + off);
        o.x = pk2h(bflo(v.x), bfhi(v.x));
        o.y = pk2h(bflo(v.y), bfhi(v.y));
    }
    *(uint2*)(wf16 + e) = o;
}

// ---------------------------------------------------------------------------
// Precompute gx = x . W_g[:, :256]^T + b_g, f16.
// Output layout is PRE-SWIZZLED for the scan (linear global_load_lds staging
// lands it conflict-free in LDS):
//   half_idx = sl*49152 + (b>>4)*12288
//            + g*4096 + (col>>4)*256 + (b&3)*64 + ((b>>2)&3)*16 + (col&15)
// so a scan read instruction's 64 lanes cover 128 contiguous bytes.
// ---------------------------------------------------------------------------
__global__ __launch_bounds__(256, 2) void gru_pre(
    const void* __restrict__ x, const u16* __restrict__ wf16,
    const void* __restrict__ br, const void* __restrict__ bz, const void* __restrict__ bh,
    u16* __restrict__ gxc, int s0, int lgSc, const void* __restrict__ Wsniff)
{
    const int f32 = sniff_fp32(Wsniff);
    const int tid = threadIdx.x;
    const int R0 = blockIdx.x * 64;
    const int msk = (1 << lgSc) - 1;

    __shared__ __align__(16) _Float16 As[64][264];   // f16, +8 pad

    {
        const int i = tid >> 2;
        const int kq = (tid & 3) * 64;
        const int m = R0 + i;
        const int b = m >> lgSc;
        const int sl = m & msk;
        const size_t xbase = ((size_t)(b * 2048 + s0 + sl)) * 256 + kq;
        u16* dst = (u16*)&As[i][kq];
        if (f32) {
            const float4* p = (const float4*)((const float*)x + xbase);
#pragma unroll
            for (int j = 0; j < 8; ++j) {
                float4 v0 = p[2 * j], v1 = p[2 * j + 1];
                uint4 o;
                o.x = pk2h(v0.x, v0.y);
                o.y = pk2h(v0.z, v0.w);
                o.z = pk2h(v1.x, v1.y);
                o.w = pk2h(v1.z, v1.w);
                *(uint4*)(dst + j * 8) = o;
            }
        } else {
            const uint4* p = (const uint4*)((const u16*)x + xbase);
#pragma unroll
            for (int j = 0; j < 8; ++j) {
                uint4 v = p[j];
                uint4 o;
                o.x = pk2h(bflo(v.x), bfhi(v.x));
                o.y = pk2h(bflo(v.y), bfhi(v.y));
                o.z = pk2h(bflo(v.z), bfhi(v.z));
                o.w = pk2h(bflo(v.w), bfhi(v.w));
                *(uint4*)(dst + j * 8) = o;
            }
        }
    }
    __syncthreads();

    const int wv = tid >> 6;
    const int lane = tid & 63;
    const int q = lane >> 4, l16 = lane & 15;

    for (int j = 0; j < 3; ++j) {
        const int gi = wv * 3 + j;            // 0..11
        const int g = gi >> 2;
        const int col0 = (gi & 3) * 64;
        const void* bias = (g == 0) ? br : ((g == 1) ? bz : bh);
        const size_t wbase = (size_t)(g * 256 + col0 + l16) * 512 + q * 8;

        f32x4 acc[4][4];
#pragma unroll
        for (int mt = 0; mt < 4; ++mt)
#pragma unroll
            for (int nt = 0; nt < 4; ++nt) acc[mt][nt] = (f32x4){0, 0, 0, 0};

#pragma unroll
        for (int k0 = 0; k0 < 256; k0 += 32) {
            f16x8 bfr[4];
#pragma unroll
            for (int nt = 0; nt < 4; ++nt)
                bfr[nt] = *(const f16x8*)(wf16 + wbase + (size_t)nt * 8192 + k0);
#pragma unroll
            for (int mt = 0; mt < 4; ++mt) {
                f16x8 af = *(const f16x8*)&As[mt * 16 + l16][k0 + q * 8];
#pragma unroll
                for (int nt = 0; nt < 4; ++nt)
                    acc[mt][nt] = MFMAH(af, bfr[nt], acc[mt][nt]);
            }
        }
#pragma unroll
        for (int nt = 0; nt < 4; ++nt) {
            const int col = col0 + nt * 16 + l16;
            const float bv = load1f(bias, col, f32);
            const int colhi = (col0 >> 4) + nt;
#pragma unroll
            for (int mt = 0; mt < 4; ++mt)
#pragma unroll
                for (int r = 0; r < 4; ++r) {
                    const int m = R0 + mt * 16 + q * 4 + r;
                    const int b = m >> lgSc;
                    const int sl = m & msk;
                    const size_t hidx = (size_t)sl * 49152 + (size_t)(b >> 4) * 12288
                        + (size_t)(g * 4096 + colhi * 256 + (b & 3) * 64
                                   + ((b >> 2) & 3) * 16 + l16);
                    gxc[hidx] = f2h(acc[mt][nt][r] + bv);
                }
        }
    }
}

// ---------------------------------------------------------------------------
// Async global->LDS staging of one step's 24 KB gx slice (3 vmem instrs per
// wave; uniform LDS base + lane*16). Counted by vmcnt.
// ---------------------------------------------------------------------------
__device__ __forceinline__ void stage_gx(const u16* gsrc, _Float16* lbuf,
                                         int wv, int lane) {
#if __has_builtin(__builtin_amdgcn_global_load_lds)
#pragma unroll
    for (int i = 0; i < 3; ++i) {
        const void* g = (const void*)((const char*)gsrc + wv * 3072 + i * 1024 + lane * 16);
        void* l = (void*)((char*)lbuf + wv * 3072 + i * 1024);
        __builtin_amdgcn_global_load_lds(
            (const __attribute__((address_space(1))) void*)g,
            (__attribute__((address_space(3))) void*)l, 16, 0, 0);
    }
#else
#pragma unroll
    for (int i = 0; i < 3; ++i) {
        uint4 v = *(const uint4*)((const char*)gsrc + wv * 3072 + i * 1024 + lane * 16);
        *(uint4*)((char*)lbuf + wv * 3072 + i * 1024 + lane * 16) = v;
    }
#endif
}

// ---------------------------------------------------------------------------
// Sequential scan v3: counted-vmcnt pipeline.
// Grid 4 x 512 (8 waves, launch_bounds(512,2) -> 256 reg cap). Per step:
//   stage gx(s+2) [3 vm] ; hs store h(s-1) [1 vm] ; ph1 MFMA ;
//   vmcnt(7) ; ph1 epilogue (gx reads, conflict-free) ; lgkm0+bar ;
//   ph2 MFMA ; ph2 epilogue (update h) ; lgkm0+bar.
// vmcnt(7) proof: >=10 vmem ops issue after batch-s starts (3 batch + 7
// newer) in ALL iterations (issue pattern is uniform; boundary steps clamp
// addresses instead of skipping), so <=7 outstanding => batch s retired.
// ---------------------------------------------------------------------------
__global__ __launch_bounds__(512, 2) void gru_scan(
    const u16* __restrict__ gxc,   // [Sc][4 blk][12288] f16, pre-swizzled
    const u16* __restrict__ wf16,  // [3][256][512] f16
    float* __restrict__ h_state,
    u16* __restrict__ hs,          // [64][Sc][256] f16
    void* __restrict__ outbase,    // h_last at element 33554432
    const void* __restrict__ Wsniff,
    int Sc, int first, int last)
{
    const int f32o = sniff_fp32(Wsniff);
    const int tid = threadIdx.x;
    const int wv = tid >> 6, lane = tid & 63;
    const int q = lane >> 4, l16 = lane & 15;
    const int b0 = blockIdx.x * 16;

    __shared__ __align__(16) _Float16 h_h[16][776];    // +8 pad: stride 97*16B
    __shared__ __align__(16) _Float16 rh_h[16][776];
    __shared__ __align__(16) _Float16 gxl[3][12288];   // linear (staged direct)

    // ---- persistent weights: ph1 {r0,r1,z0,z1}, ph2 {h0,h1} ----
    f16x8 w1[4][8];
#pragma unroll
    for (int t = 0; t < 4; ++t) {
        const int g = t >> 1;
        const size_t rowb =
            (size_t)(g * 256 + wv * 32 + (t & 1) * 16 + l16) * 512 + 256 + q * 8;
#pragma unroll
        for (int kk = 0; kk < 8; ++kk)
            w1[t][kk] = *(const f16x8*)(wf16 + rowb + kk * 32);
    }
    f16x8 w2[2][8];
#pragma unroll
    for (int t = 0; t < 2; ++t) {
        const size_t rowb = (size_t)(512 + wv * 32 + t * 16 + l16) * 512 + 256 + q * 8;
#pragma unroll
    for (int kk = 0; kk < 8; ++kk)
            w2[t][kk] = *(const f16x8*)(wf16 + rowb + kk * 32);
    }

    // ---- init h (registers + LDS f16) ----
    float h_old[2][4];
#pragma unroll
    for (int t = 0; t < 2; ++t) {
        const int col = wv * 32 + t * 16 + l16;
#pragma unroll
        for (int r = 0; r < 4; ++r) {
            const int b = q * 4 + r;
            float h0 = first ? 0.f : h_state[(size_t)(b0 + b) * 256 + col];
            h_old[t][r] = h0;
            h_h[b][col] = (_Float16)h0;
        }
    }
    BAR();   // h_h visible before hs-stream reads it

    const u16* gbase = gxc + (size_t)blockIdx.x * 12288;
    _Float16* g_cur = &gxl[0][0];
    _Float16* g_nx1 = &gxl[1][0];
    _Float16* g_nx2 = &gxl[2][0];

    // prologue: stage s=0, s=1 (6 vmem)
    stage_gx(gbase, g_cur, wv, lane);
    stage_gx(gbase + (size_t)((Sc > 1) ? 1 : 0) * 49152, g_nx1, wv, lane);

    const int cb = tid >> 5, cc = (tid & 31) * 8;   // hs-stream mapping

    for (int s = 0; s < Sc; ++s) {
        // stage gx(min(s+2, Sc-1)) -> g_nx2  (3 vmem, uniform every step)
        {
            int ss = s + 2;
            if (ss > Sc - 1) ss = Sc - 1;
            stage_gx(gbase + (size_t)ss * 49152, g_nx2, wv, lane);
        }
        // stream h(s-1) (h_init at s=0, overwritten at s=1) (1 vmem, uniform)
        {
            const int slot = (s > 0) ? (s - 1) : 0;
            uint4 hv = *(const uint4*)&h_h[cb][cc];
            *(uint4*)(hs + ((size_t)(b0 + cb) * Sc + slot) * 256 + cc) = hv;
        }

        // ---- phase 1 MFMA: r and z (A = h_h, B = w1 regs) ----
        f32x4 acc[4];
#pragma unroll
        for (int t = 0; t < 4; ++t) acc[t] = (f32x4){0.f, 0.f, 0.f, 0.f};
#pragma unroll
        for (int kk = 0; kk < 8; ++kk) {
            f16x8 a = *(const f16x8*)&h_h[l16][kk * 32 + q * 8];
#pragma unroll
            for (int t = 0; t < 4; ++t) acc[t] = MFMAH(a, w1[t][kk], acc[t]);
        }

        WAITV7();   // batch s staged -> g_cur valid

        // ---- phase 1 epilogue: conflict-free gx reads, sigmoid ----
        float z_reg[2][4];
#pragma unroll
        for (int t = 0; t < 4; ++t) {
            const int g = t >> 1;
            const int tt = t & 1;
            const int col = wv * 32 + tt * 16 + l16;
            const int gb = g * 4096 + (wv * 2 + tt) * 256 + q * 16 + l16;
#pragma unroll
            for (int r = 0; r < 4; ++r) {
                float gx = (float)g_cur[gb + r * 64];
                float p = acc[t][r] + gx;
                float sg = frcp(1.f + fexp2(-1.44269504f * p));
                if (g == 0) rh_h[q * 4 + r][col] = (_Float16)(sg * h_old[tt][r]);
                else        z_reg[tt][r] = sg;
            }
        }
        BAR();

        // ---- phase 2: h~ (A = rh_h, B = w2 regs) + update ----
        f32x4 acch[2];
#pragma unroll
        for (int t = 0; t < 2; ++t) acch[t] = (f32x4){0.f, 0.f, 0.f, 0.f};
#pragma unroll
        for (int kk = 0; kk < 8; ++kk) {
            f16x8 a = *(const f16x8*)&rh_h[l16][kk * 32 + q * 8];
#pragma unroll
            for (int t = 0; t < 2; ++t) acch[t] = MFMAH(a, w2[t][kk], acch[t]);
        }
#pragma unroll
        for (int t = 0; t < 2; ++t) {
            const int col = wv * 32 + t * 16 + l16;
            const int gb = 8192 + (wv * 2 + t) * 256 + q * 16 + l16;
#pragma unroll
            for (int r = 0; r < 4; ++r) {
                const int b = q * 4 + r;
                float gx = (float)g_cur[gb + r * 64];
                float p = acch[t][r] + gx;
                p = fminf(fmaxf(p, -15.f), 15.f);
                float e = fexp2(2.88539008f * p);
                float ht = 1.f - 2.f * frcp(e + 1.f);
                float hold = h_old[t][r];
                float hn = fmaf(z_reg[t][r], ht - hold, hold);
                h_old[t][r] = hn;
                h_h[b][col] = (_Float16)hn;
                if (s == Sc - 1) {
                    h_state[(size_t)(b0 + b) * 256 + col] = hn;
                    if (last) {
                        const size_t li = (size_t)33554432 + (size_t)(b0 + b) * 256 + col;
                        if (f32o) ((float*)outbase)[li] = hn;
                        else      ((u16*)outbase)[li] = f2bf(hn);
                    }
                }
            }
        }
        // rotate gx triple-buffer
        _Float16* tmp = g_cur; g_cur = g_nx1; g_nx1 = g_nx2; g_nx2 = tmp;
        BAR();
    }
    // final hs row: h(Sc-1)
    {
        uint4 hv = *(const uint4*)&h_h[cb][cc];
        *(uint4*)(hs + ((size_t)(b0 + cb) * Sc + (Sc - 1)) * 256 + cc) = hv;
    }
}

// ---------------------------------------------------------------------------
// Output projection: reads hs (f16, ws) and wfc16 (f16, ws), writes d_out.
// ---------------------------------------------------------------------------
__global__ __launch_bounds__(256) void gru_proj(
    const u16* __restrict__ wfc16, const void* __restrict__ bfc,
    const void* __restrict__ Wsniff, const u16* __restrict__ hs,
    void* __restrict__ outb, int s0, int lgSc)
{
    const int f32 = sniff_fp32(Wsniff);
    const int lane = threadIdx.x & 63;
    const int wave = threadIdx.x >> 6;
    const int q = lane >> 4, l16 = lane & 15;
    const int msk = (1 << lgSc) - 1;
    const int m0 = blockIdx.x * 64 + wave * 16;
    const size_t aidx = (size_t)(m0 + l16) * 256 + q * 8;
    const size_t widx = (size_t)l16 * 256 + q * 8;
    f32x4 acc[16];
#pragma unroll
    for (int t = 0; t < 16; ++t) acc[t] = (f32x4){0, 0, 0, 0};
#pragma unroll 2
    for (int k0 = 0; k0 < 256; k0 += 32) {
        f16x8 af = *(const f16x8*)(hs + aidx + k0);
#pragma unroll
        for (int t = 0; t < 16; ++t) {
            f16x8 bfg = *(const f16x8*)(wfc16 + widx + (size_t)t * 4096 + k0);
            acc[t] = MFMAH(af, bfg, acc[t]);
        }
    }
#pragma unroll
    for (int t = 0; t < 16; ++t) {
        const int col = t * 16 + l16;
        const float bv = load1f(bfc, col, f32);
#pragma unroll
        for (int r = 0; r < 4; ++r) {
            const int m = m0 + q * 4 + r;
            const int b = m >> lgSc;
            const int sl = m & msk;
            const size_t oidx = ((size_t)b * 2048 + s0 + sl) * 256 + col;
            float v = acc[t][r] + bv;
            if (f32) ((float*)outb)[oidx] = v;
            else     ((u16*)outb)[oidx] = f2bf(v);
        }
    }
}

// ---------------------------------------------------------------------------
extern "C" void kernel_launch(void* const* d_in, const int* in_sizes, int n_in,
                              void* d_out, int out_size, void* d_ws, size_t ws_size,
                              hipStream_t stream) {
    (void)in_sizes; (void)n_in; (void)out_size;
    const void* x   = d_in[0];
    const void* Wr  = d_in[1];
    const void* br  = d_in[2];
    const void* Wz  = d_in[3];
    const void* bz  = d_in[4];
    const void* Wh  = d_in[5];
    const void* bh  = d_in[6];
    const void* Wfc = d_in[7];
    const void* bfc = d_in[8];

    float* h_state = (float*)d_ws;                        // 64*256 fp32 = 64KB
    u16*   wf16    = (u16*)((char*)d_ws + 65536);         // 458752 halfs

    int lgSc = 11;
    while (lgSc > 0 &&
           (size_t)1048576 + ((size_t)131072 << lgSc) > ws_size) --lgSc;
    const int Sc = 1 << lgSc;
    u16* gxc = (u16*)((char*)d_ws + 1048576);
    u16* hs  = (u16*)((char*)d_ws + 1048576 + (size_t)Sc * 98304);

    wconv<<<448, 256, 0, stream>>>(Wr, Wz, Wh, Wfc, wf16);

    for (int s0 = 0; s0 < 2048; s0 += Sc) {
        gru_pre<<<Sc, 256, 0, stream>>>(x, wf16, br, bz, bh, gxc, s0, lgSc, Wr);
        gru_scan<<<4, 512, 0, stream>>>(gxc, wf16, h_state, hs, d_out, Wr,
                                        Sc, (s0 == 0) ? 1 : 0,
                                        (s0 + Sc == 2048) ? 1 : 0);
        gru_proj<<<Sc, 256, 0, stream>>>(wf16 + 393216, bfc, Wr, hs, d_out,
                                         s0, lgSc);
    }
}

// Round 4
// 5296.861 us; speedup vs baseline: 2.7691x; 1.0405x over previous
//
#include <hip/hip_runtime.h>
#include <hip/hip_bf16.h>
#include <hip/hip_fp16.h>

typedef unsigned short u16;
typedef unsigned int u32;
typedef __attribute__((ext_vector_type(4))) float f32x4;
typedef __attribute__((ext_vector_type(8))) _Float16 f16x8;
typedef __attribute__((ext_vector_type(4))) _Float16 f16x4;

#define MFMAH(a, b, c) __builtin_amdgcn_mfma_f32_16x16x32_f16((a), (b), (c), 0, 0, 0)

// Raw barrier: LDS-drain only -- does NOT drain vmcnt (keeps global_load_lds
// prefetch in flight across barriers).
#define BAR() asm volatile("s_waitcnt lgkmcnt(0)\ns_barrier" ::: "memory")
// Counted vmem wait, pinned on BOTH sides so the static vmcnt arithmetic
// can't be perturbed by scheduler motion (rule #18).
#define WAITV7()                                          \
    do {                                                  \
        __builtin_amdgcn_sched_barrier(0);                \
        asm volatile("s_waitcnt vmcnt(7)" ::: "memory");  \
        __builtin_amdgcn_sched_barrier(0);                \
    } while (0)

__device__ __forceinline__ float bflo(u32 u) { return __uint_as_float(u << 16); }
__device__ __forceinline__ float bfhi(u32 u) { return __uint_as_float(u & 0xffff0000u); }
__device__ __forceinline__ float bf1(u16 u) { return __uint_as_float(((u32)u) << 16); }
__device__ __forceinline__ u16 f2bf(float f) {
    __hip_bfloat16 b = __float2bfloat16(f);
    return __builtin_bit_cast(u16, b);
}
__device__ __forceinline__ u16 f2h(float f) { return __builtin_bit_cast(u16, (_Float16)f); }
__device__ __forceinline__ u32 pk2h(float a, float b) {
    return (u32)f2h(a) | ((u32)f2h(b) << 16);
}
__device__ __forceinline__ float fexp2(float x) { return __builtin_amdgcn_exp2f(x); }
__device__ __forceinline__ float frcp(float x) { return __builtin_amdgcn_rcpf(x); }

// ---------------------------------------------------------------------------
// Wave-uniform dtype sniff: 1 = fp32 inputs, 0 = bf16.
// ---------------------------------------------------------------------------
__device__ __forceinline__ int sniff_fp32(const void* Wr) {
    const uint4* p = (const uint4*)Wr;
    uint4 v = p[threadIdx.x & 15];
    u32 a[4] = {v.x, v.y, v.z, v.w};
    float m = 0.f;
#pragma unroll
    for (int i = 0; i < 4; ++i) {
        float lo = fabsf(bflo(a[i])), hi = fabsf(bfhi(a[i]));
        if (!(lo < 1e30f)) lo = 1e30f;
        if (!(hi < 1e30f)) hi = 1e30f;
        m = fmaxf(m, fmaxf(lo, hi));
    }
#pragma unroll
    for (int off = 32; off; off >>= 1) m = fmaxf(m, __shfl_xor(m, off, 64));
    return m > 100.f ? 1 : 0;
}

__device__ __forceinline__ float load1f(const void* base, size_t idx, int f32) {
    return f32 ? ((const float*)base)[idx] : bf1(((const u16*)base)[idx]);
}

// ---------------------------------------------------------------------------
// One-shot weight convert to f16 in ws, PRE-SCALED:
//   W_r/W_z recurrent half (cols 256..511) *= -log2(e)
//   W_h recurrent half *= 2*log2(e)
// so the scan's sigmoid is rcp(1+exp2(acc)) and tanh is 1-2*rcp(exp2(acc)+1).
// Layout: wf16[g][n][512] g=0..2, then wfc16[o][256] at half-offset 393216.
// ---------------------------------------------------------------------------
__global__ void wconv(const void* __restrict__ Wr, const void* __restrict__ Wz,
                      const void* __restrict__ Wh, const void* __restrict__ Wfc,
                      u16* __restrict__ wf16)
{
    const int f32 = sniff_fp32(Wr);
    const int gid = blockIdx.x * 256 + threadIdx.x;
    const int e = gid * 4;
    const void* src;
    int off;
    float sc = 1.f;
    if (e < 131072)      { src = Wr;  off = e; }
    else if (e < 262144) { src = Wz;  off = e - 131072; }
    else if (e < 393216) { src = Wh;  off = e - 262144; }
    else                 { src = Wfc; off = e - 393216; }
    if (e < 393216 && (off & 511) >= 256)
        sc = (e < 262144) ? -1.442695041f : 2.885390082f;
    float4 v;
    if (f32) {
        v = *(const float4*)((const float*)src + off);
    } else {
        uint2 u = *(const uint2*)((const u16*)src + off);
        v.x = bflo(u.x); v.y = bfhi(u.x); v.z = bflo(u.y); v.w = bfhi(u.y);
    }
    uint2 o;
    o.x = pk2h(v.x * sc, v.y * sc);
    o.y = pk2h(v.z * sc, v.w * sc);
    *(uint2*)(wf16 + e) = o;
}

// ---------------------------------------------------------------------------
// Precompute gx = (x . W_g[:, :256]^T + b_g) * scale_g, f16, where
// scale_{r,z} = -log2e, scale_h = 2*log2e (matches pre-scaled scan weights).
// Output layout: per step-slice [64 batch-block of 16][8 waves][6 tiles][256]:
//   hidx = sl*49152 + (b>>4)*12288 + (col>>5)*1536
//        + (g*2 + ((col>>4)&1))*256 + (bb>>2)*64 + (col&15)*4 + (bb&3)
// (bb = b&15). One scan wave's 6 tiles are contiguous 1536 halfs -> each wave
// stages ITS OWN slice (no cross-wave vmcnt dependency), and each lane's 4
// batch-values are contiguous (ds_read_b64, conflict-free).
// ---------------------------------------------------------------------------
__global__ __launch_bounds__(256, 2) void gru_pre(
    const void* __restrict__ x, const u16* __restrict__ wf16,
    const void* __restrict__ br, const void* __restrict__ bz, const void* __restrict__ bh,
    u16* __restrict__ gxc, int s0, int lgSc, const void* __restrict__ Wsniff)
{
    const int f32 = sniff_fp32(Wsniff);
    const int tid = threadIdx.x;
    const int R0 = blockIdx.x * 64;
    const int msk = (1 << lgSc) - 1;

    __shared__ __align__(16) _Float16 As[64][264];   // f16, +8 pad

    {
        const int i = tid >> 2;
        const int kq = (tid & 3) * 64;
        const int m = R0 + i;
        const int b = m >> lgSc;
        const int sl = m & msk;
        const size_t xbase = ((size_t)(b * 2048 + s0 + sl)) * 256 + kq;
        u16* dst = (u16*)&As[i][kq];
        if (f32) {
            const float4* p = (const float4*)((const float*)x + xbase);
#pragma unroll
            for (int j = 0; j < 8; ++j) {
                float4 v0 = p[2 * j], v1 = p[2 * j + 1];
                uint4 o;
                o.x = pk2h(v0.x, v0.y);
                o.y = pk2h(v0.z, v0.w);
                o.z = pk2h(v1.x, v1.y);
                o.w = pk2h(v1.z, v1.w);
                *(uint4*)(dst + j * 8) = o;
            }
        } else {
            const uint4* p = (const uint4*)((const u16*)x + xbase);
#pragma unroll
            for (int j = 0; j < 8; ++j) {
                uint4 v = p[j];
                uint4 o;
                o.x = pk2h(bflo(v.x), bfhi(v.x));
                o.y = pk2h(bflo(v.y), bfhi(v.y));
                o.z = pk2h(bflo(v.z), bfhi(v.z));
                o.w = pk2h(bflo(v.w), bfhi(v.w));
                *(uint4*)(dst + j * 8) = o;
            }
        }
    }
    __syncthreads();

    const int wv = tid >> 6;
    const int lane = tid & 63;
    const int q = lane >> 4, l16 = lane & 15;

    for (int j = 0; j < 3; ++j) {
        const int gi = wv * 3 + j;            // 0..11
        const int g = gi >> 2;
        const int col0 = (gi & 3) * 64;
        const void* bias = (g == 0) ? br : ((g == 1) ? bz : bh);
        const float cg = (g < 2) ? -1.442695041f : 2.885390082f;
        const size_t wbase = (size_t)(g * 256 + col0 + l16) * 512 + q * 8;

        f32x4 acc[4][4];
#pragma unroll
        for (int mt = 0; mt < 4; ++mt)
#pragma unroll
            for (int nt = 0; nt < 4; ++nt) acc[mt][nt] = (f32x4){0, 0, 0, 0};

#pragma unroll
        for (int k0 = 0; k0 < 256; k0 += 32) {
            f16x8 bfr[4];
#pragma unroll
            for (int nt = 0; nt < 4; ++nt)
                bfr[nt] = *(const f16x8*)(wf16 + wbase + (size_t)nt * 8192 + k0);
#pragma unroll
            for (int mt = 0; mt < 4; ++mt) {
                f16x8 af = *(const f16x8*)&As[mt * 16 + l16][k0 + q * 8];
#pragma unroll
                for (int nt = 0; nt < 4; ++nt)
                    acc[mt][nt] = MFMAH(af, bfr[nt], acc[mt][nt]);
            }
        }
#pragma unroll
        for (int nt = 0; nt < 4; ++nt) {
            const int col = col0 + nt * 16 + l16;
            const float bv = load1f(bias, col, f32);
            const int colpart = (col >> 5) * 1536 + (g * 2 + ((col >> 4) & 1)) * 256
                                + (col & 15) * 4;
#pragma unroll
            for (int mt = 0; mt < 4; ++mt)
#pragma unroll
                for (int r = 0; r < 4; ++r) {
                    const int m = R0 + mt * 16 + q * 4 + r;
                    const int b = m >> lgSc;
                    const int sl = m & msk;
                    const int bb = b & 15;
                    const size_t hidx = (size_t)sl * 49152 + (size_t)(b >> 4) * 12288
                        + (size_t)(colpart + (bb >> 2) * 64 + (bb & 3));
                    gxc[hidx] = f2h((acc[mt][nt][r] + bv) * cg);
                }
        }
    }
}

// ---------------------------------------------------------------------------
// Async global->LDS staging of one step's 24 KB gx slice. Wave wv copies
// bytes [wv*3072, wv*3072+3072) -- exactly its OWN 6 tiles (see gru_pre
// layout), so its vmcnt certifies everything it will read. 3 vmem per wave.
// ---------------------------------------------------------------------------
__device__ __forceinline__ void stage_gx(const u16* gsrc, _Float16* lbuf,
                                         int wv, int lane) {
#if __has_builtin(__builtin_amdgcn_global_load_lds)
#pragma unroll
    for (int i = 0; i < 3; ++i) {
        const void* g = (const void*)((const char*)gsrc + wv * 3072 + i * 1024 + lane * 16);
        void* l = (void*)((char*)lbuf + wv * 3072 + i * 1024);
        __builtin_amdgcn_global_load_lds(
            (const __attribute__((address_space(1))) void*)g,
            (__attribute__((address_space(3))) void*)l, 16, 0, 0);
    }
#else
#pragma unroll
    for (int i = 0; i < 3; ++i) {
        uint4 v = *(const uint4*)((const char*)gsrc + wv * 3072 + i * 1024 + lane * 16);
        *(uint4*)((char*)lbuf + wv * 3072 + i * 1024 + lane * 16) = v;
    }
#endif
}

// ---------------------------------------------------------------------------
// Sequential scan v4: critical-path surgery.
//  - gx read as ds_read_b64 (4 values/lane contiguous), used as the MFMA
//    C-INITIALIZER (kills acc zero-init and the acc+gx add).
//  - weights pre-scaled by -log2e / 2log2e -> sigmoid = rcp(1+exp2(acc)),
//    tanh = 1-2*rcp(exp2(acc)+1); IEEE inf/0 saturate exactly (no clamps).
//  - z-gate sigmoid moved AFTER the mid barrier (overlaps ph2 MFMA latency).
//  - each wave stages + reads its own gx slice (no cross-wave vmem race).
// ---------------------------------------------------------------------------
__global__ __launch_bounds__(512, 2) void gru_scan(
    const u16* __restrict__ gxc,   // [Sc][4 blk][12288] f16, swizzled+scaled
    const u16* __restrict__ wf16,  // [3][256][512] f16, recurrent half scaled
    float* __restrict__ h_state,
    u16* __restrict__ hs,          // [64][Sc][256] f16
    void* __restrict__ outbase,    // h_last at element 33554432
    const void* __restrict__ Wsniff,
    int Sc, int first, int last)
{
    const int f32o = sniff_fp32(Wsniff);
    const int tid = threadIdx.x;
    const int wv = tid >> 6, lane = tid & 63;
    const int q = lane >> 4, l16 = lane & 15;
    const int b0 = blockIdx.x * 16;

    __shared__ __align__(16) _Float16 h_h[16][264];
    __shared__ __align__(16) _Float16 rh_h[16][264];
    __shared__ __align__(16) _Float16 gxl[3][12288];

    // ---- persistent weights: ph1 {r0,r1,z0,z1}, ph2 {h0,h1} ----
    f16x8 w1[4][8];
#pragma unroll
    for (int t = 0; t < 4; ++t) {
        const int g = t >> 1;
        const size_t rowb =
            (size_t)(g * 256 + wv * 32 + (t & 1) * 16 + l16) * 512 + 256 + q * 8;
#pragma unroll
        for (int kk = 0; kk < 8; ++kk)
            w1[t][kk] = *(const f16x8*)(wf16 + rowb + kk * 32);
    }
    f16x8 w2[2][8];
#pragma unroll
    for (int t = 0; t < 2; ++t) {
        const size_t rowb = (size_t)(512 + wv * 32 + t * 16 + l16) * 512 + 256 + q * 8;
#pragma unroll
        for (int kk = 0; kk < 8; ++kk)
            w2[t][kk] = *(const f16x8*)(wf16 + rowb + kk * 32);
    }

    // ---- init h ----
    float h_old[2][4];
#pragma unroll
    for (int t = 0; t < 2; ++t) {
        const int col = wv * 32 + t * 16 + l16;
#pragma unroll
        for (int r = 0; r < 4; ++r) {
            const int b = q * 4 + r;
            float h0 = first ? 0.f : h_state[(size_t)(b0 + b) * 256 + col];
            h_old[t][r] = h0;
            h_h[b][col] = (_Float16)h0;
        }
    }
    BAR();

    const u16* gbase = gxc + (size_t)blockIdx.x * 12288;
    _Float16* g_cur = &gxl[0][0];
    _Float16* g_nx1 = &gxl[1][0];
    _Float16* g_nx2 = &gxl[2][0];

    stage_gx(gbase, g_cur, wv, lane);
    stage_gx(gbase + (size_t)((Sc > 1) ? 1 : 0) * 49152, g_nx1, wv, lane);

    const int cb = tid >> 5, cc = (tid & 31) * 8;           // hs-stream map
    const int gxoff = wv * 1536 + (q * 16 + l16) * 4;       // + tile*256

    for (int s = 0; s < Sc; ++s) {
        // stage gx(min(s+2,Sc-1)) (3 vmem), stream h(s-1) (1 vmem) -- both
        // issue patterns uniform every step so the vmcnt(7) proof holds.
        {
            int ss = s + 2;
            if (ss > Sc - 1) ss = Sc - 1;
            stage_gx(gbase + (size_t)ss * 49152, g_nx2, wv, lane);
        }
        {
            const int slot = (s > 0) ? (s - 1) : 0;
            uint4 hv = *(const uint4*)&h_h[cb][cc];
            *(uint4*)(hs + ((size_t)(b0 + cb) * Sc + slot) * 256 + cc) = hv;
        }

        WAITV7();   // own stage(s) retired -> g_cur valid for this wave

        // ---- gx -> C initializers (r0,r1,z0,z1) ----
        f32x4 accr[2], accz[2];
#pragma unroll
        for (int t = 0; t < 2; ++t) {
            f16x4 gr = *(const f16x4*)&g_cur[gxoff + t * 256];
            f16x4 gz = *(const f16x4*)&g_cur[gxoff + (2 + t) * 256];
#pragma unroll
            for (int r = 0; r < 4; ++r) { accr[t][r] = (float)gr[r]; accz[t][r] = (float)gz[r]; }
        }
        // ---- ph1 MFMA: A = h_h ----
        f16x8 a[8];
#pragma unroll
        for (int kk = 0; kk < 8; ++kk)
            a[kk] = *(const f16x8*)&h_h[l16][kk * 32 + q * 8];
#pragma unroll
        for (int kk = 0; kk < 8; ++kk) {
            accr[0] = MFMAH(a[kk], w1[0][kk], accr[0]);
            accr[1] = MFMAH(a[kk], w1[1][kk], accr[1]);
        }
#pragma unroll
        for (int kk = 0; kk < 8; ++kk) {
            accz[0] = MFMAH(a[kk], w1[2][kk], accz[0]);
            accz[1] = MFMAH(a[kk], w1[3][kk], accz[1]);
        }
        // ---- r epilogue only (z deferred past the barrier) ----
#pragma unroll
        for (int t = 0; t < 2; ++t) {
            const int col = wv * 32 + t * 16 + l16;
#pragma unroll
            for (int r = 0; r < 4; ++r) {
                float sg = frcp(1.f + fexp2(accr[t][r]));
                rh_h[q * 4 + r][col] = (_Float16)(sg * h_old[t][r]);
            }
        }
        BAR();

        // ---- ph2: h~ MFMA (C from gx), z sigmoid in the shadow ----
        f32x4 acch[2];
#pragma unroll
        for (int t = 0; t < 2; ++t) {
            f16x4 gh = *(const f16x4*)&g_cur[gxoff + (4 + t) * 256];
#pragma unroll
            for (int r = 0; r < 4; ++r) acch[t][r] = (float)gh[r];
        }
        f16x8 bfr[8];
#pragma unroll
        for (int kk = 0; kk < 8; ++kk)
            bfr[kk] = *(const f16x8*)&rh_h[l16][kk * 32 + q * 8];
        float zz[2][4];
#pragma unroll
        for (int t = 0; t < 2; ++t)
#pragma unroll
            for (int r = 0; r < 4; ++r) zz[t][r] = frcp(1.f + fexp2(accz[t][r]));
#pragma unroll
        for (int kk = 0; kk < 8; ++kk) {
            acch[0] = MFMAH(bfr[kk], w2[0][kk], acch[0]);
            acch[1] = MFMAH(bfr[kk], w2[1][kk], acch[1]);
        }
#pragma unroll
        for (int t = 0; t < 2; ++t) {
            const int col = wv * 32 + t * 16 + l16;
#pragma unroll
            for (int r = 0; r < 4; ++r) {
                const int b = q * 4 + r;
                float e = fexp2(acch[t][r]);
                float ht = fmaf(-2.f, frcp(e + 1.f), 1.f);
                float hold = h_old[t][r];
                float hn = fmaf(zz[t][r], ht - hold, hold);
                h_old[t][r] = hn;
                h_h[b][col] = (_Float16)hn;
                if (s == Sc - 1) {
                    h_state[(size_t)(b0 + b) * 256 + col] = hn;
                    if (last) {
                        const size_t li = (size_t)33554432 + (size_t)(b0 + b) * 256 + col;
                        if (f32o) ((float*)outbase)[li] = hn;
                        else      ((u16*)outbase)[li] = f2bf(hn);
                    }
                }
            }
        }
        _Float16* tmp = g_cur; g_cur = g_nx1; g_nx1 = g_nx2; g_nx2 = tmp;
        BAR();
    }
    // final hs row: h(Sc-1)
    {
        uint4 hv = *(const uint4*)&h_h[cb][cc];
        *(uint4*)(hs + ((size_t)(b0 + cb) * Sc + (Sc - 1)) * 256 + cc) = hv;
    }
}

// ---------------------------------------------------------------------------
// Output projection: reads hs (f16, ws) and wfc16 (f16, ws), writes d_out.
// ---------------------------------------------------------------------------
__global__ __launch_bounds__(256) void gru_proj(
    const u16* __restrict__ wfc16, const void* __restrict__ bfc,
    const void* __restrict__ Wsniff, const u16* __restrict__ hs,
    void* __restrict__ outb, int s0, int lgSc)
{
    const int f32 = sniff_fp32(Wsniff);
    const int lane = threadIdx.x & 63;
    const int wave = threadIdx.x >> 6;
    const int q = lane >> 4, l16 = lane & 15;
    const int msk = (1 << lgSc) - 1;
    const int m0 = blockIdx.x * 64 + wave * 16;
    const size_t aidx = (size_t)(m0 + l16) * 256 + q * 8;
    const size_t widx = (size_t)l16 * 256 + q * 8;
    f32x4 acc[16];
#pragma unroll
    for (int t = 0; t < 16; ++t) acc[t] = (f32x4){0, 0, 0, 0};
#pragma unroll 2
    for (int k0 = 0; k0 < 256; k0 += 32) {
        f16x8 af = *(const f16x8*)(hs + aidx + k0);
#pragma unroll
        for (int t = 0; t < 16; ++t) {
            f16x8 bfg = *(const f16x8*)(wfc16 + widx + (size_t)t * 4096 + k0);
            acc[t] = MFMAH(af, bfg, acc[t]);
        }
    }
#pragma unroll
    for (int t = 0; t < 16; ++t) {
        const int col = t * 16 + l16;
        const float bv = load1f(bfc, col, f32);
#pragma unroll
        for (int r = 0; r < 4; ++r) {
            const int m = m0 + q * 4 + r;
            const int b = m >> lgSc;
            const int sl = m & msk;
            const size_t oidx = ((size_t)b * 2048 + s0 + sl) * 256 + col;
            float v = acc[t][r] + bv;
            if (f32) ((float*)outb)[oidx] = v;
            else     ((u16*)outb)[oidx] = f2bf(v);
        }
    }
}

// ---------------------------------------------------------------------------
extern "C" void kernel_launch(void* const* d_in, const int* in_sizes, int n_in,
                              void* d_out, int out_size, void* d_ws, size_t ws_size,
                              hipStream_t stream) {
    (void)in_sizes; (void)n_in; (void)out_size;
    const void* x   = d_in[0];
    const void* Wr  = d_in[1];
    const void* br  = d_in[2];
    const void* Wz  = d_in[3];
    const void* bz  = d_in[4];
    const void* Wh  = d_in[5];
    const void* bh  = d_in[6];
    const void* Wfc = d_in[7];
    const void* bfc = d_in[8];

    float* h_state = (float*)d_ws;                        // 64*256 fp32 = 64KB
    u16*   wf16    = (u16*)((char*)d_ws + 65536);         // 458752 halfs

    int lgSc = 11;
    while (lgSc > 0 &&
           (size_t)1048576 + ((size_t)131072 << lgSc) > ws_size) --lgSc;
    const int Sc = 1 << lgSc;
    u16* gxc = (u16*)((char*)d_ws + 1048576);
    u16* hs  = (u16*)((char*)d_ws + 1048576 + (size_t)Sc * 98304);

    wconv<<<448, 256, 0, stream>>>(Wr, Wz, Wh, Wfc, wf16);

    for (int s0 = 0; s0 < 2048; s0 += Sc) {
        gru_pre<<<Sc, 256, 0, stream>>>(x, wf16, br, bz, bh, gxc, s0, lgSc, Wr);
        gru_scan<<<4, 512, 0, stream>>>(gxc, wf16, h_state, hs, d_out, Wr,
                                        Sc, (s0 == 0) ? 1 : 0,
                                        (s0 + Sc == 2048) ? 1 : 0);
        gru_proj<<<Sc, 256, 0, stream>>>(wf16 + 393216, bfc, Wr, hs, d_out,
                                         s0, lgSc);
    }
}